// Round 6
// baseline (439.758 us; speedup 1.0000x reference)
//
#include <hip/hip_runtime.h>
#include <hip/hip_bf16.h>
#include <math.h>

// ---------------------------------------------------------------------------
// SimpleMoEModel: dense GEMM -> top1-MoE -> top1-MoE -> residual -> mean ->
// log_softmax -> NLL.  B=8 S=2048 D=1024 E=8, capacity = T/E = 2048.
//
// Round 6 (stage fusion):
//  - Gating fused into producing-GEMM epilogue: C-tile -> LDS (bf16) ->
//    16x16x32 MFMA vs staged Wg[n0..n0+128][8] B-frag -> atomicAdd fp32
//    partial logits (m120 round-trip pattern). k_gate_mm launches removed.
//  - k_route reads logits, computes argmax+softmax+gate, scans, and zeroes
//    dropped rows itself (k_zero_rows removed, idx buffer removed).
//  - Dense epilogue emits h-part of sent (tile rows are batch-uniform);
//    k_reduce reads o2 only.
//  - One combined prep kernel (W transpose + Wg pack + x convert).
//  - GEMM core unchanged: BK=64, global_load_lds w=16, XOR swizzle,
//    XCD-aware 1D grids (r5: expert FETCH 137->32.5 MB verified).
// ---------------------------------------------------------------------------

#define TOKS 16384
#define DIM 1024
#define NEXP 8
#define CAP 2048
#define BATCH 8
#define SEQ 2048

typedef __bf16 bf16_t;
typedef __bf16 bf16x8 __attribute__((ext_vector_type(8)));
typedef float fx4 __attribute__((ext_vector_type(4)));

__device__ __forceinline__ void gll16(const bf16_t* g, bf16_t* l) {
  __builtin_amdgcn_global_load_lds(
      (const __attribute__((address_space(1))) unsigned int*)g,
      (__attribute__((address_space(3))) unsigned int*)l, 16, 0, 0);
}

// ---------------- combined prep: W transpose+cvt | Wg pack | x cvt ---------
#define PW_BLOCKS (17 * 256)
#define CVT_BLOCKS (TOKS * DIM / 8 / 256)
__global__ __launch_bounds__(256) void k_prep(
    const float* __restrict__ W1, const float* __restrict__ We2,
    const float* __restrict__ We3, const float* __restrict__ Wg2,
    const float* __restrict__ Wg3, const float* __restrict__ x,
    bf16_t* __restrict__ Wt, bf16_t* __restrict__ WgP,
    bf16_t* __restrict__ xb) {
  const int id = blockIdx.x;
  const int tid = threadIdx.x;
  if (id < PW_BLOCKS) {
    __shared__ float t[64][65];
    const int m = id >> 8, rem = id & 255;
    const int n0 = (rem & 15) * 64, k0 = (rem >> 4) * 64;
    const float* src = (m == 0) ? W1
                       : (m <= 8) ? We2 + (size_t)(m - 1) * DIM * DIM
                                  : We3 + (size_t)(m - 9) * DIM * DIM;
    bf16_t* dst = Wt + (size_t)m * DIM * DIM;
    const int r = tid >> 4, c4 = (tid & 15) * 4;
#pragma unroll
    for (int i = 0; i < 4; i++) {
      float4 v = *(const float4*)&src[(size_t)(k0 + i * 16 + r) * DIM + n0 + c4];
      t[i * 16 + r][c4] = v.x;
      t[i * 16 + r][c4 + 1] = v.y;
      t[i * 16 + r][c4 + 2] = v.z;
      t[i * 16 + r][c4 + 3] = v.w;
    }
    __syncthreads();
#pragma unroll
    for (int i = 0; i < 4; i++) {
      int rn = i * 16 + r;
      union { bf16_t b[4]; uint2 u; } tmp;
#pragma unroll
      for (int j = 0; j < 4; j++) tmp.b[j] = (bf16_t)t[c4 + j][rn];
      *(uint2*)&dst[(size_t)(n0 + rn) * DIM + k0 + c4] = tmp.u;
    }
  } else if (id < PW_BLOCKS + 2) {
    const int which = id - PW_BLOCKS;
    const float* src = which ? Wg3 : Wg2;
    bf16_t* dst = WgP + which * (128 * 8 * 8);
#pragma unroll
    for (int j = 0; j < 4; j++) {
      int d = tid * 4 + j;
      float4 a = *(const float4*)&src[d * 8];
      float4 b = *(const float4*)&src[d * 8 + 4];
      float v[8] = {a.x, a.y, a.z, a.w, b.x, b.y, b.z, b.w};
#pragma unroll
      for (int e = 0; e < 8; e++)
        dst[((d >> 3) * 8 + e) * 8 + (d & 7)] = (bf16_t)v[e];
    }
  } else {
    const int cid = id - PW_BLOCKS - 2;
    size_t i = ((size_t)cid * 256 + tid) * 8;
    float4 a = *(const float4*)&x[i];
    float4 b = *(const float4*)&x[i + 4];
    union { bf16_t h[8]; uint4 u; } t;
    t.h[0] = (bf16_t)a.x; t.h[1] = (bf16_t)a.y; t.h[2] = (bf16_t)a.z; t.h[3] = (bf16_t)a.w;
    t.h[4] = (bf16_t)b.x; t.h[5] = (bf16_t)b.y; t.h[6] = (bf16_t)b.z; t.h[7] = (bf16_t)b.w;
    *(uint4*)&xb[i] = t.u;
  }
}

// ---------------- dense GEMM + fused logits2 + fused sent(h) ---------------
// hs tile stride 136 elems (272 B: 16B-aligned rows, tolerable bank pattern).
#define HSTRIDE 136
__global__ __launch_bounds__(256) void k_gemm_dense(
    const bf16_t* __restrict__ A, const bf16_t* __restrict__ Bt,
    const float* __restrict__ bias, const bf16_t* __restrict__ WgP2,
    bf16_t* __restrict__ out, float* __restrict__ logits,
    float* __restrict__ sent) {
  __shared__ alignas(16) bf16_t smem[128 * HSTRIDE];  // As|Bs in-loop, hs after
  __shared__ alignas(16) bf16_t WgN[1024];            // Wg[n0..n0+128][8] B-frag
  bf16_t* As = smem;
  bf16_t* Bs = smem + 128 * 64;
  const int tid = threadIdx.x;
  const int lane = tid & 63, wave = tid >> 6;
  const int quad = lane >> 4, l15 = lane & 15;
  const int wr = (wave >> 1) * 64, wc = (wave & 1) * 64;
  const int id = blockIdx.x;
  const int j_ = id >> 3;
  const int m0 = ((id & 7) * 16 + (j_ >> 3)) * 128;  // XCD-aware decode
  const int n0 = (j_ & 7) * 128;
  const int kc = (tid & 7) ^ ((tid >> 3) & 7);
  const int rbase = tid >> 3;

  // stage WgN once (per-lane global addr! r4 lesson)
  if (wave == 0) {
    gll16(WgP2 + n0 * 8 + lane * 8, WgN);
    gll16(WgP2 + n0 * 8 + 512 + lane * 8, WgN + 512);
  }

  const bf16_t* gA[4];
  const bf16_t* gB[4];
  bf16_t* lA[4];
  bf16_t* lB[4];
#pragma unroll
  for (int i = 0; i < 4; i++) {
    int r = rbase + 32 * i;
    gA[i] = A + (size_t)(m0 + r) * DIM + kc * 8;
    gB[i] = Bt + (size_t)(n0 + r) * DIM + kc * 8;
    lA[i] = &As[(wave * 64 + 256 * i) * 8];
    lB[i] = &Bs[(wave * 64 + 256 * i) * 8];
  }

  fx4 acc[4][4];
#pragma unroll
  for (int i = 0; i < 4; i++)
#pragma unroll
    for (int j = 0; j < 4; j++) acc[i][j] = (fx4)0.0f;

  for (int k0 = 0; k0 < DIM; k0 += 64) {
#pragma unroll
    for (int i = 0; i < 4; i++) gll16(gA[i] + k0, lA[i]);
#pragma unroll
    for (int i = 0; i < 4; i++) gll16(gB[i] + k0, lB[i]);
    __syncthreads();
#pragma unroll
    for (int s = 0; s < 2; s++) {
      const int pofs = ((s * 4 + quad) ^ (l15 & 7)) << 3;
      bf16x8 av[4], bv[4];
#pragma unroll
      for (int i = 0; i < 4; i++)
        av[i] = *(const bf16x8*)&As[(wr + i * 16 + l15) * 64 + pofs];
#pragma unroll
      for (int j = 0; j < 4; j++)
        bv[j] = *(const bf16x8*)&Bs[(wc + j * 16 + l15) * 64 + pofs];
#pragma unroll
      for (int i = 0; i < 4; i++)
#pragma unroll
        for (int j = 0; j < 4; j++)
          acc[i][j] = __builtin_amdgcn_mfma_f32_16x16x32_bf16(av[i], bv[j], acc[i][j], 0, 0, 0);
    }
    __syncthreads();
  }
  // epilogue: store h + write bf16 tile into hs
  bf16_t* hs = smem;
#pragma unroll
  for (int j = 0; j < 4; j++) {
    int colL = wc + j * 16 + l15;
    float bb = bias[n0 + colL];
#pragma unroll
    for (int i = 0; i < 4; i++)
#pragma unroll
      for (int r = 0; r < 4; r++) {
        int rowL = wr + i * 16 + quad * 4 + r;
        bf16_t hv = (bf16_t)(acc[i][j][r] + bb);
        out[(size_t)(m0 + rowL) * DIM + n0 + colL] = hv;
        hs[rowL * HSTRIDE + colL] = hv;
      }
  }
  __syncthreads();
  // fused logits: rows wave*32..+32, K=128 local cols, B-frag = WgN
  fx4 lac0 = (fx4)0.0f, lac1 = (fx4)0.0f;
#pragma unroll
  for (int ks = 0; ks < 4; ks++) {
    bf16x8 bv = *(const bf16x8*)&WgN[((ks * 4 + quad) * 8 + (l15 & 7)) * 8];
    bf16x8 av0 = *(const bf16x8*)&hs[(wave * 32 + l15) * HSTRIDE + ks * 32 + quad * 8];
    bf16x8 av1 = *(const bf16x8*)&hs[(wave * 32 + 16 + l15) * HSTRIDE + ks * 32 + quad * 8];
    lac0 = __builtin_amdgcn_mfma_f32_16x16x32_bf16(av0, bv, lac0, 0, 0, 0);
    lac1 = __builtin_amdgcn_mfma_f32_16x16x32_bf16(av1, bv, lac1, 0, 0, 0);
  }
  if (l15 < 8) {
#pragma unroll
    for (int r = 0; r < 4; r++) {
      atomicAdd(&logits[(m0 + wave * 32 + quad * 4 + r) * 8 + l15], lac0[r]);
      atomicAdd(&logits[(m0 + wave * 32 + 16 + quad * 4 + r) * 8 + l15], lac1[r]);
    }
  }
  // fused sent(h): tile rows all in batch b = m0>>11
  {
    const int colL = tid & 127, rg = tid >> 7;
    float ss = 0.f;
#pragma unroll 8
    for (int rr = 0; rr < 64; rr++) ss += (float)hs[(rg * 64 + rr) * HSTRIDE + colL];
    atomicAdd(&sent[(m0 >> 11) * DIM + n0 + colL], ss * (1.0f / SEQ));
  }
}

// ---------------- routing: argmax+softmax+scan+zero from logits ------------
__global__ __launch_bounds__(1024) void k_route(
    const float* __restrict__ logits, int* __restrict__ tok,
    int* __restrict__ cnt, float* __restrict__ gate,
    bf16_t* __restrict__ obuf) {
  const int e = blockIdx.x;
  const int tid = threadIdx.x, lane = tid & 63, wv = tid >> 6;
  __shared__ int wsum[16];
  __shared__ int dlist[2048];
  int m[16];
  int c = 0;
#pragma unroll
  for (int j = 0; j < 16; j++) {
    int t = tid * 16 + j;
    const float* lp = logits + t * 8;
    float4 a = *(const float4*)lp, b = *(const float4*)(lp + 4);
    float l[8] = {a.x, a.y, a.z, a.w, b.x, b.y, b.z, b.w};
    float best = l[0];
    int bi = 0;
#pragma unroll
    for (int k = 1; k < 8; k++)
      if (l[k] > best) { best = l[k]; bi = k; }  // strict >: first max wins
    m[j] = (bi == e);
    if (m[j]) {
      float s = 0.f;
#pragma unroll
      for (int k = 0; k < 8; k++) s += expf(l[k] - best);
      gate[t] = 1.0f / s;
      c++;
    }
  }
  int sc = c;
#pragma unroll
  for (int off = 1; off < 64; off <<= 1) {
    int n = __shfl_up(sc, off);
    if (lane >= off) sc += n;
  }
  if (lane == 63) wsum[wv] = sc;
  __syncthreads();
  int wb = 0, tot = 0;
#pragma unroll
  for (int i = 0; i < 16; i++) {
    int s = wsum[i];
    tot += s;
    if (i < wv) wb += s;
  }
  int pos = wb + sc - c;
  const uint4 z = {0u, 0u, 0u, 0u};
#pragma unroll
  for (int j = 0; j < 16; j++) {
    if (m[j]) {
      int t = tid * 16 + j;
      if (pos < CAP) {
        tok[e * CAP + pos] = t;
      } else {
        int di = pos - CAP;
        if (di < 2048) dlist[di] = t;
        else  // pathological overflow: zero directly
          for (int k = 0; k < 128; k++) *(uint4*)&obuf[(size_t)t * DIM + k * 8] = z;
      }
      pos++;
    }
  }
  if (tid == 0) cnt[e] = tot < CAP ? tot : CAP;
  __syncthreads();
  int ndl = tot - CAP;
  ndl = ndl < 0 ? 0 : (ndl > 2048 ? 2048 : ndl);
  const int grp = tid >> 7, li = tid & 127;
  for (int d = grp; d < ndl; d += 8) {
    int t = dlist[d];
    *(uint4*)&obuf[(size_t)t * DIM + li * 8] = z;
  }
}

// ---------------- expert GEMM (+ optional fused next-layer logits) ---------
template <bool FG>
__global__ __launch_bounds__(256) void k_gemm_expert(
    const bf16_t* __restrict__ Ain, const bf16_t* __restrict__ Wt,
    const float* __restrict__ be, const int* __restrict__ tok,
    const int* __restrict__ cnt, const float* __restrict__ gate,
    const bf16_t* __restrict__ zp, bf16_t* __restrict__ outp,
    const bf16_t* __restrict__ WgPn, float* __restrict__ logits) {
  const int id = blockIdx.x;
  const int e = id & 7;  // XCD-aware: expert = XCD slot (weights L2-resident)
  const int j_ = id >> 3;
  const int c0 = (j_ >> 3) * 128;
  const int n0 = (j_ & 7) * 128;
  const int count = cnt[e];
  if (c0 >= count) return;
  const bf16_t* Bt = Wt + (size_t)e * DIM * DIM;
  const float* bias = be + (size_t)e * DIM;
  const int* tk = tok + e * CAP;

  __shared__ alignas(16) bf16_t smem[128 * HSTRIDE];
  __shared__ alignas(16) bf16_t WgN[1024];
  bf16_t* As = smem;
  bf16_t* Bs = smem + 128 * 64;
  const int tid = threadIdx.x;
  const int lane = tid & 63, wave = tid >> 6;
  const int quad = lane >> 4, l15 = lane & 15;
  const int wr = (wave >> 1) * 64, wc = (wave & 1) * 64;
  const int kc = (tid & 7) ^ ((tid >> 3) & 7);
  const int rbase = tid >> 3;

  if (FG && wave == 0) {
    gll16(WgPn + n0 * 8 + lane * 8, WgN);
    gll16(WgPn + n0 * 8 + 512 + lane * 8, WgN + 512);
  }

  const bf16_t* gA[4];
  const bf16_t* gB[4];
  bf16_t* lA[4];
  bf16_t* lB[4];
#pragma unroll
  for (int i = 0; i < 4; i++) {
    int r = rbase + 32 * i;
    int ca = c0 + r;
    gA[i] = (ca < count) ? Ain + (size_t)tk[ca] * DIM + kc * 8 : zp;
    gB[i] = Bt + (size_t)(n0 + r) * DIM + kc * 8;
    lA[i] = &As[(wave * 64 + 256 * i) * 8];
    lB[i] = &Bs[(wave * 64 + 256 * i) * 8];
  }

  fx4 acc[4][4];
#pragma unroll
  for (int i = 0; i < 4; i++)
#pragma unroll
    for (int j = 0; j < 4; j++) acc[i][j] = (fx4)0.0f;

  for (int k0 = 0; k0 < DIM; k0 += 64) {
#pragma unroll
    for (int i = 0; i < 4; i++) gll16(gA[i] + k0, lA[i]);
#pragma unroll
    for (int i = 0; i < 4; i++) gll16(gB[i] + k0, lB[i]);
    __syncthreads();
#pragma unroll
    for (int s = 0; s < 2; s++) {
      const int pofs = ((s * 4 + quad) ^ (l15 & 7)) << 3;
      bf16x8 av[4], bv[4];
#pragma unroll
      for (int i = 0; i < 4; i++)
        av[i] = *(const bf16x8*)&As[(wr + i * 16 + l15) * 64 + pofs];
#pragma unroll
      for (int j = 0; j < 4; j++)
        bv[j] = *(const bf16x8*)&Bs[(wc + j * 16 + l15) * 64 + pofs];
#pragma unroll
      for (int i = 0; i < 4; i++)
#pragma unroll
        for (int j = 0; j < 4; j++)
          acc[i][j] = __builtin_amdgcn_mfma_f32_16x16x32_bf16(av[i], bv[j], acc[i][j], 0, 0, 0);
    }
    __syncthreads();
  }
  // epilogue: out[t] = gate[t]*(acc+bias); optionally stash tile for logits
  bf16_t* hs = smem;
#pragma unroll
  for (int i = 0; i < 4; i++)
#pragma unroll
    for (int r = 0; r < 4; r++) {
      int rowL = wr + i * 16 + quad * 4 + r;
      int c = c0 + rowL;
      bool ok = c < count;
      int t = 0;
      float g = 0.f;
      if (ok) { t = tk[c]; g = gate[t]; }
#pragma unroll
      for (int j = 0; j < 4; j++) {
        int colL = wc + j * 16 + l15;
        float v = ok ? (acc[i][j][r] + bias[n0 + colL]) * g : 0.f;
        bf16_t vb = (bf16_t)v;
        if (FG) hs[rowL * HSTRIDE + colL] = vb;
        if (ok) outp[(size_t)t * DIM + n0 + colL] = vb;
      }
    }
  if (FG) {
    __syncthreads();
    fx4 lac0 = (fx4)0.0f, lac1 = (fx4)0.0f;
#pragma unroll
    for (int ks = 0; ks < 4; ks++) {
      bf16x8 bv = *(const bf16x8*)&WgN[((ks * 4 + quad) * 8 + (l15 & 7)) * 8];
      bf16x8 av0 = *(const bf16x8*)&hs[(wave * 32 + l15) * HSTRIDE + ks * 32 + quad * 8];
      bf16x8 av1 = *(const bf16x8*)&hs[(wave * 32 + 16 + l15) * HSTRIDE + ks * 32 + quad * 8];
      lac0 = __builtin_amdgcn_mfma_f32_16x16x32_bf16(av0, bv, lac0, 0, 0, 0);
      lac1 = __builtin_amdgcn_mfma_f32_16x16x32_bf16(av1, bv, lac1, 0, 0, 0);
    }
    if (l15 < 8) {
#pragma unroll
      for (int r = 0; r < 4; r++) {
        int ca = c0 + wave * 32 + quad * 4 + r;
        int cb = ca + 16;
        if (ca < count) atomicAdd(&logits[tk[ca] * 8 + l15], lac0[r]);
        if (cb < count) atomicAdd(&logits[tk[cb] * 8 + l15], lac1[r]);
      }
    }
  }
}

// ---------------- sent += mean_s(o2) (h-part fused into dense) -------------
__global__ __launch_bounds__(256) void k_reduce_o2(
    const bf16_t* __restrict__ o2, float* __restrict__ sent) {
  const int tid = threadIdx.x;
  const int d8 = (tid & 127) * 8;
  const int sg = tid >> 7;
  const int b = blockIdx.y;
  const int s0 = blockIdx.x * 64 + sg * 32;
  float acc[8] = {0.f, 0.f, 0.f, 0.f, 0.f, 0.f, 0.f, 0.f};
  const size_t base = ((size_t)b * SEQ + s0) * DIM + d8;
  for (int i = 0; i < 32; i++) {
    union { bf16_t v[8]; uint4 u; } oo;
    oo.u = *(const uint4*)&o2[base + (size_t)i * DIM];
#pragma unroll
    for (int j = 0; j < 8; j++) acc[j] += (float)oo.v[j];
  }
#pragma unroll
  for (int j = 0; j < 8; j++)
    atomicAdd(&sent[b * DIM + d8 + j], acc[j] * (1.0f / SEQ));
}

// ---------------- loss: one block per batch, atomicAdd into out ------------
__global__ __launch_bounds__(256) void k_loss(
    const float* __restrict__ sent, const int* __restrict__ y,
    float* __restrict__ out) {
  const int b = blockIdx.x, tid = threadIdx.x;
  const float* sb = sent + b * DIM;
  __shared__ float red[256];
  float m = -1e30f;
  for (int d = tid; d < DIM; d += 256) m = fmaxf(m, sb[d]);
  red[tid] = m;
  __syncthreads();
  for (int s = 128; s; s >>= 1) {
    if (tid < s) red[tid] = fmaxf(red[tid], red[tid + s]);
    __syncthreads();
  }
  m = red[0];
  __syncthreads();
  float sum = 0.f;
  for (int d = tid; d < DIM; d += 256) sum += expf(sb[d] - m);
  red[tid] = sum;
  __syncthreads();
  for (int s = 128; s; s >>= 1) {
    if (tid < s) red[tid] += red[tid + s];
    __syncthreads();
  }
  if (tid == 0) atomicAdd(out, (m + logf(red[0]) - sb[y[b]]) * (1.0f / BATCH));
}

// ---------------------------------------------------------------------------
extern "C" void kernel_launch(void* const* d_in, const int* in_sizes, int n_in,
                              void* d_out, int out_size, void* d_ws, size_t ws_size,
                              hipStream_t stream) {
  (void)in_sizes; (void)n_in; (void)out_size; (void)ws_size;
  const float* x   = (const float*)d_in[0];
  const int*   y   = (const int*)d_in[1];
  const float* W1  = (const float*)d_in[2];
  const float* b1  = (const float*)d_in[3];
  const float* Wg2 = (const float*)d_in[4];
  const float* We2 = (const float*)d_in[5];
  const float* be2 = (const float*)d_in[6];
  const float* Wg3 = (const float*)d_in[7];
  const float* We3 = (const float*)d_in[8];
  const float* be3 = (const float*)d_in[9];

  char* p = (char*)d_ws;
  size_t off = 0;
  auto carve = [&](size_t bytes) -> char* {
    char* r = p + off;
    off += (bytes + 255) & ~(size_t)255;
    return r;
  };
  bf16_t* Wt   = (bf16_t*)carve((size_t)17 * DIM * DIM * 2);  // 0:W1t 1..8:We2t 9..16:We3t
  bf16_t* WgP  = (bf16_t*)carve(2 * 128 * 8 * 8 * 2);         // gate B-frag packs
  bf16_t* h    = (bf16_t*)carve((size_t)TOKS * DIM * 2);
  bf16_t* o1   = (bf16_t*)carve((size_t)TOKS * DIM * 2);
  bf16_t* o2   = (bf16_t*)carve((size_t)TOKS * DIM * 2);  // aliases xb lifetime
  float*  gate = (float*)carve(TOKS * 4);
  int*    tok  = (int*)carve(NEXP * CAP * 4);
  int*    cnt  = (int*)carve(NEXP * 4);
  // --- contiguous zero region: sent, zp, logits2, logits3 (single memset) --
  size_t zoff0 = off;
  float*  sent = (float*)carve(BATCH * DIM * 4);
  bf16_t* zp   = (bf16_t*)carve(4096);
  float*  lg2  = (float*)carve(TOKS * 8 * 4);
  float*  lg3  = (float*)carve(TOKS * 8 * 4);
  size_t zbytes = off - zoff0;
  bf16_t* xb   = o2;  // x-bf16 dead before o2 is born

  hipMemsetAsync(sent, 0, zbytes, stream);  // sent + zp + logits2 + logits3
  hipMemsetAsync(d_out, 0, 4, stream);      // loss accumulates via atomics

  // prep: W transpose+cvt (17x256 blocks) | Wg pack (2) | x cvt (8192)
  k_prep<<<PW_BLOCKS + 2 + CVT_BLOCKS, 256, 0, stream>>>(
      W1, We2, We3, Wg2, Wg3, x, Wt, WgP, xb);

  // dense pre-layer (+ logits2, + sent h-part)
  k_gemm_dense<<<(TOKS / 128) * (DIM / 128), 256, 0, stream>>>(
      xb, Wt, b1, WgP, h, lg2, sent);

  // MoE layer 2 (expert GEMM fuses logits3)
  k_route<<<NEXP, 1024, 0, stream>>>(lg2, tok, cnt, gate, o1);
  k_gemm_expert<true><<<NEXP * (CAP / 128) * (DIM / 128), 256, 0, stream>>>(
      h, Wt + (size_t)1 * DIM * DIM, be2, tok, cnt, gate, zp, o1,
      WgP + 128 * 8 * 8, lg3);

  // MoE layer 3
  k_route<<<NEXP, 1024, 0, stream>>>(lg3, tok, cnt, gate, o2);
  k_gemm_expert<false><<<NEXP * (CAP / 128) * (DIM / 128), 256, 0, stream>>>(
      o1, Wt + (size_t)9 * DIM * DIM, be3, tok, cnt, gate, zp, o2,
      nullptr, nullptr);

  // sent += mean_s(o2); CE loss
  k_reduce_o2<<<dim3(SEQ / 64, BATCH), 256, 0, stream>>>(o2, sent);
  k_loss<<<BATCH, 256, 0, stream>>>(sent, y, (float*)d_out);
}

// Round 7
// 431.790 us; speedup vs baseline: 1.0185x; 1.0185x over previous
//
#include <hip/hip_runtime.h>
#include <hip/hip_bf16.h>
#include <math.h>

// ---------------------------------------------------------------------------
// SimpleMoEModel: dense GEMM -> top1-MoE -> top1-MoE -> residual -> mean ->
// log_softmax -> NLL.  B=8 S=2048 D=1024 E=8, capacity = T/E = 2048.
//
// Round 7 (fix r6's occupancy regression, keep the fusion):
//  - LDS exactly 32 KB (r6's 36.8 KB cost a co-resident block: 5->4/CU,
//    expert GEMM 58->82 us). hs tile = 128x128 XOR-swizzled over As|Bs,
//    WgN B-frags read from global (L2-hot 2 KB) instead of LDS.
//  - Dense sent-part from acc registers (shfl over quads + atomics),
//    no LDS re-read loop.
//  - Everything else as r6: fused logits epilogues, k_route does
//    argmax+softmax+scan+drop-zeroing, single prep kernel, XCD-aware grids.
// ---------------------------------------------------------------------------

#define TOKS 16384
#define DIM 1024
#define NEXP 8
#define CAP 2048
#define BATCH 8
#define SEQ 2048

typedef __bf16 bf16_t;
typedef __bf16 bf16x8 __attribute__((ext_vector_type(8)));
typedef float fx4 __attribute__((ext_vector_type(4)));

__device__ __forceinline__ void gll16(const bf16_t* g, bf16_t* l) {
  __builtin_amdgcn_global_load_lds(
      (const __attribute__((address_space(1))) unsigned int*)g,
      (__attribute__((address_space(3))) unsigned int*)l, 16, 0, 0);
}

// swizzled 128x128 bf16 tile: chunk' = chunk ^ (row&15); keeps ds_read_b128
// of 8 k-consecutive elems conflict-free while fitting exactly 32 KB.
__device__ __forceinline__ int hsw(int row, int col) {
  return row * 128 + ((((col >> 3) ^ (row & 15)) << 3) | (col & 7));
}

// ---------------- combined prep: W transpose+cvt | Wg pack | x cvt ---------
#define PW_BLOCKS (17 * 256)
#define CVT_BLOCKS (TOKS * DIM / 8 / 256)
__global__ __launch_bounds__(256) void k_prep(
    const float* __restrict__ W1, const float* __restrict__ We2,
    const float* __restrict__ We3, const float* __restrict__ Wg2,
    const float* __restrict__ Wg3, const float* __restrict__ x,
    bf16_t* __restrict__ Wt, bf16_t* __restrict__ WgP,
    bf16_t* __restrict__ xb) {
  const int id = blockIdx.x;
  const int tid = threadIdx.x;
  if (id < PW_BLOCKS) {
    __shared__ float t[64][65];
    const int m = id >> 8, rem = id & 255;
    const int n0 = (rem & 15) * 64, k0 = (rem >> 4) * 64;
    const float* src = (m == 0) ? W1
                       : (m <= 8) ? We2 + (size_t)(m - 1) * DIM * DIM
                                  : We3 + (size_t)(m - 9) * DIM * DIM;
    bf16_t* dst = Wt + (size_t)m * DIM * DIM;
    const int r = tid >> 4, c4 = (tid & 15) * 4;
#pragma unroll
    for (int i = 0; i < 4; i++) {
      float4 v = *(const float4*)&src[(size_t)(k0 + i * 16 + r) * DIM + n0 + c4];
      t[i * 16 + r][c4] = v.x;
      t[i * 16 + r][c4 + 1] = v.y;
      t[i * 16 + r][c4 + 2] = v.z;
      t[i * 16 + r][c4 + 3] = v.w;
    }
    __syncthreads();
#pragma unroll
    for (int i = 0; i < 4; i++) {
      int rn = i * 16 + r;
      union { bf16_t b[4]; uint2 u; } tmp;
#pragma unroll
      for (int j = 0; j < 4; j++) tmp.b[j] = (bf16_t)t[c4 + j][rn];
      *(uint2*)&dst[(size_t)(n0 + rn) * DIM + k0 + c4] = tmp.u;
    }
  } else if (id < PW_BLOCKS + 2) {
    const int which = id - PW_BLOCKS;
    const float* src = which ? Wg3 : Wg2;
    bf16_t* dst = WgP + which * (128 * 8 * 8);
#pragma unroll
    for (int j = 0; j < 4; j++) {
      int d = tid * 4 + j;
      float4 a = *(const float4*)&src[d * 8];
      float4 b = *(const float4*)&src[d * 8 + 4];
      float v[8] = {a.x, a.y, a.z, a.w, b.x, b.y, b.z, b.w};
#pragma unroll
      for (int e = 0; e < 8; e++)
        dst[((d >> 3) * 8 + e) * 8 + (d & 7)] = (bf16_t)v[e];
    }
  } else {
    const int cid = id - PW_BLOCKS - 2;
    size_t i = ((size_t)cid * 256 + tid) * 8;
    float4 a = *(const float4*)&x[i];
    float4 b = *(const float4*)&x[i + 4];
    union { bf16_t h[8]; uint4 u; } t;
    t.h[0] = (bf16_t)a.x; t.h[1] = (bf16_t)a.y; t.h[2] = (bf16_t)a.z; t.h[3] = (bf16_t)a.w;
    t.h[4] = (bf16_t)b.x; t.h[5] = (bf16_t)b.y; t.h[6] = (bf16_t)b.z; t.h[7] = (bf16_t)b.w;
    *(uint4*)&xb[i] = t.u;
  }
}

// ---------------- dense GEMM + fused logits2 + fused sent(h) ---------------
__global__ __launch_bounds__(256) void k_gemm_dense(
    const bf16_t* __restrict__ A, const bf16_t* __restrict__ Bt,
    const float* __restrict__ bias, const bf16_t* __restrict__ WgP2,
    bf16_t* __restrict__ out, float* __restrict__ logits,
    float* __restrict__ sent) {
  __shared__ alignas(16) bf16_t smem[128 * 128];  // 32 KB: As|Bs, then hs
  bf16_t* As = smem;
  bf16_t* Bs = smem + 128 * 64;
  const int tid = threadIdx.x;
  const int lane = tid & 63, wave = tid >> 6;
  const int quad = lane >> 4, l15 = lane & 15;
  const int wr = (wave >> 1) * 64, wc = (wave & 1) * 64;
  const int id = blockIdx.x;
  const int j_ = id >> 3;
  const int m0 = ((id & 7) * 16 + (j_ >> 3)) * 128;  // XCD-aware decode
  const int n0 = (j_ & 7) * 128;
  const int kc = (tid & 7) ^ ((tid >> 3) & 7);
  const int rbase = tid >> 3;

  const bf16_t* gA[4];
  const bf16_t* gB[4];
  bf16_t* lA[4];
  bf16_t* lB[4];
#pragma unroll
  for (int i = 0; i < 4; i++) {
    int r = rbase + 32 * i;
    gA[i] = A + (size_t)(m0 + r) * DIM + kc * 8;
    gB[i] = Bt + (size_t)(n0 + r) * DIM + kc * 8;
    lA[i] = &As[(wave * 64 + 256 * i) * 8];
    lB[i] = &Bs[(wave * 64 + 256 * i) * 8];
  }

  fx4 acc[4][4];
#pragma unroll
  for (int i = 0; i < 4; i++)
#pragma unroll
    for (int j = 0; j < 4; j++) acc[i][j] = (fx4)0.0f;

  for (int k0 = 0; k0 < DIM; k0 += 64) {
#pragma unroll
    for (int i = 0; i < 4; i++) gll16(gA[i] + k0, lA[i]);
#pragma unroll
    for (int i = 0; i < 4; i++) gll16(gB[i] + k0, lB[i]);
    __syncthreads();
#pragma unroll
    for (int s = 0; s < 2; s++) {
      const int pofs = ((s * 4 + quad) ^ (l15 & 7)) << 3;
      bf16x8 av[4], bv[4];
#pragma unroll
      for (int i = 0; i < 4; i++)
        av[i] = *(const bf16x8*)&As[(wr + i * 16 + l15) * 64 + pofs];
#pragma unroll
      for (int j = 0; j < 4; j++)
        bv[j] = *(const bf16x8*)&Bs[(wc + j * 16 + l15) * 64 + pofs];
#pragma unroll
      for (int i = 0; i < 4; i++)
#pragma unroll
        for (int j = 0; j < 4; j++)
          acc[i][j] = __builtin_amdgcn_mfma_f32_16x16x32_bf16(av[i], bv[j], acc[i][j], 0, 0, 0);
    }
    __syncthreads();
  }
  // ---- epilogue: h store + swizzled hs stash + register sent partials ----
  bf16_t* hs = smem;
  float bb[4], sj[4] = {0.f, 0.f, 0.f, 0.f};
#pragma unroll
  for (int j = 0; j < 4; j++) bb[j] = bias[n0 + wc + j * 16 + l15];
#pragma unroll
  for (int i = 0; i < 4; i++)
#pragma unroll
    for (int r = 0; r < 4; r++) {
      int rowL = wr + i * 16 + quad * 4 + r;
#pragma unroll
      for (int j = 0; j < 4; j++) {
        int colL = wc + j * 16 + l15;
        float v = acc[i][j][r] + bb[j];
        sj[j] += v;
        bf16_t hv = (bf16_t)v;
        out[(size_t)(m0 + rowL) * DIM + n0 + colL] = hv;
        hs[hsw(rowL, colL)] = hv;
      }
    }
  // sent(h): sum over the 2 quads' partial rows via shfl, 1 atomic/col/wave
#pragma unroll
  for (int j = 0; j < 4; j++) {
    sj[j] += __shfl_xor(sj[j], 16);
    sj[j] += __shfl_xor(sj[j], 32);
  }
  if (quad == 0) {
#pragma unroll
    for (int j = 0; j < 4; j++)
      atomicAdd(&sent[(m0 >> 11) * DIM + n0 + wc + j * 16 + l15],
                sj[j] * (1.0f / SEQ));
  }
  __syncthreads();
  // ---- fused logits: hs (A-frag) x Wg B-frag (from global, L2-hot) ----
  fx4 lac0 = (fx4)0.0f, lac1 = (fx4)0.0f;
#pragma unroll
  for (int ks = 0; ks < 4; ks++) {
    bf16x8 bv = *(const bf16x8*)&WgP2[(((n0 >> 3) + ks * 4 + quad) * 8 + (l15 & 7)) * 8];
    bf16x8 av0 = *(const bf16x8*)&hs[hsw(wave * 32 + l15, ks * 32 + quad * 8)];
    bf16x8 av1 = *(const bf16x8*)&hs[hsw(wave * 32 + 16 + l15, ks * 32 + quad * 8)];
    lac0 = __builtin_amdgcn_mfma_f32_16x16x32_bf16(av0, bv, lac0, 0, 0, 0);
    lac1 = __builtin_amdgcn_mfma_f32_16x16x32_bf16(av1, bv, lac1, 0, 0, 0);
  }
  if (l15 < 8) {
#pragma unroll
    for (int r = 0; r < 4; r++) {
      atomicAdd(&logits[(m0 + wave * 32 + quad * 4 + r) * 8 + l15], lac0[r]);
      atomicAdd(&logits[(m0 + wave * 32 + 16 + quad * 4 + r) * 8 + l15], lac1[r]);
    }
  }
}

// ---------------- routing: argmax+softmax+scan+zero from logits ------------
__global__ __launch_bounds__(1024) void k_route(
    const float* __restrict__ logits, int* __restrict__ tok,
    int* __restrict__ cnt, float* __restrict__ gate,
    bf16_t* __restrict__ obuf) {
  const int e = blockIdx.x;
  const int tid = threadIdx.x, lane = tid & 63, wv = tid >> 6;
  __shared__ int wsum[16];
  __shared__ int dlist[2048];
  int m[16];
  int c = 0;
#pragma unroll
  for (int j = 0; j < 16; j++) {
    int t = tid * 16 + j;
    const float* lp = logits + t * 8;
    float4 a = *(const float4*)lp, b = *(const float4*)(lp + 4);
    float l[8] = {a.x, a.y, a.z, a.w, b.x, b.y, b.z, b.w};
    float best = l[0];
    int bi = 0;
#pragma unroll
    for (int k = 1; k < 8; k++)
      if (l[k] > best) { best = l[k]; bi = k; }  // strict >: first max wins
    m[j] = (bi == e);
    if (m[j]) {
      float s = 0.f;
#pragma unroll
      for (int k = 0; k < 8; k++) s += expf(l[k] - best);
      gate[t] = 1.0f / s;
      c++;
    }
  }
  int sc = c;
#pragma unroll
  for (int off = 1; off < 64; off <<= 1) {
    int n = __shfl_up(sc, off);
    if (lane >= off) sc += n;
  }
  if (lane == 63) wsum[wv] = sc;
  __syncthreads();
  int wb = 0, tot = 0;
#pragma unroll
  for (int i = 0; i < 16; i++) {
    int s = wsum[i];
    tot += s;
    if (i < wv) wb += s;
  }
  int pos = wb + sc - c;
  const uint4 z = {0u, 0u, 0u, 0u};
#pragma unroll
  for (int j = 0; j < 16; j++) {
    if (m[j]) {
      int t = tid * 16 + j;
      if (pos < CAP) {
        tok[e * CAP + pos] = t;
      } else {
        int di = pos - CAP;
        if (di < 2048) dlist[di] = t;
        else  // pathological overflow: zero directly
          for (int k = 0; k < 128; k++) *(uint4*)&obuf[(size_t)t * DIM + k * 8] = z;
      }
      pos++;
    }
  }
  if (tid == 0) cnt[e] = tot < CAP ? tot : CAP;
  __syncthreads();
  int ndl = tot - CAP;
  ndl = ndl < 0 ? 0 : (ndl > 2048 ? 2048 : ndl);
  const int grp = tid >> 7, li = tid & 127;
  for (int d = grp; d < ndl; d += 8) {
    int t = dlist[d];
    *(uint4*)&obuf[(size_t)t * DIM + li * 8] = z;
  }
}

// ---------------- expert GEMM (+ optional fused next-layer logits) ---------
template <bool FG>
__global__ __launch_bounds__(256) void k_gemm_expert(
    const bf16_t* __restrict__ Ain, const bf16_t* __restrict__ Wt,
    const float* __restrict__ be, const int* __restrict__ tok,
    const int* __restrict__ cnt, const float* __restrict__ gate,
    const bf16_t* __restrict__ zp, bf16_t* __restrict__ outp,
    const bf16_t* __restrict__ WgPn, float* __restrict__ logits) {
  const int id = blockIdx.x;
  const int e = id & 7;  // XCD-aware: expert = XCD slot (weights L2-resident)
  const int j_ = id >> 3;
  const int c0 = (j_ >> 3) * 128;
  const int n0 = (j_ & 7) * 128;
  const int count = cnt[e];
  if (c0 >= count) return;
  const bf16_t* Bt = Wt + (size_t)e * DIM * DIM;
  const float* bias = be + (size_t)e * DIM;
  const int* tk = tok + e * CAP;

  __shared__ alignas(16) bf16_t smem[128 * 128];  // 32 KB: As|Bs, then hs
  bf16_t* As = smem;
  bf16_t* Bs = smem + 128 * 64;
  const int tid = threadIdx.x;
  const int lane = tid & 63, wave = tid >> 6;
  const int quad = lane >> 4, l15 = lane & 15;
  const int wr = (wave >> 1) * 64, wc = (wave & 1) * 64;
  const int kc = (tid & 7) ^ ((tid >> 3) & 7);
  const int rbase = tid >> 3;

  const bf16_t* gA[4];
  const bf16_t* gB[4];
  bf16_t* lA[4];
  bf16_t* lB[4];
#pragma unroll
  for (int i = 0; i < 4; i++) {
    int r = rbase + 32 * i;
    int ca = c0 + r;
    gA[i] = (ca < count) ? Ain + (size_t)tk[ca] * DIM + kc * 8 : zp;
    gB[i] = Bt + (size_t)(n0 + r) * DIM + kc * 8;
    lA[i] = &As[(wave * 64 + 256 * i) * 8];
    lB[i] = &Bs[(wave * 64 + 256 * i) * 8];
  }

  fx4 acc[4][4];
#pragma unroll
  for (int i = 0; i < 4; i++)
#pragma unroll
    for (int j = 0; j < 4; j++) acc[i][j] = (fx4)0.0f;

  for (int k0 = 0; k0 < DIM; k0 += 64) {
#pragma unroll
    for (int i = 0; i < 4; i++) gll16(gA[i] + k0, lA[i]);
#pragma unroll
    for (int i = 0; i < 4; i++) gll16(gB[i] + k0, lB[i]);
    __syncthreads();
#pragma unroll
    for (int s = 0; s < 2; s++) {
      const int pofs = ((s * 4 + quad) ^ (l15 & 7)) << 3;
      bf16x8 av[4], bv[4];
#pragma unroll
      for (int i = 0; i < 4; i++)
        av[i] = *(const bf16x8*)&As[(wr + i * 16 + l15) * 64 + pofs];
#pragma unroll
      for (int j = 0; j < 4; j++)
        bv[j] = *(const bf16x8*)&Bs[(wc + j * 16 + l15) * 64 + pofs];
#pragma unroll
      for (int i = 0; i < 4; i++)
#pragma unroll
        for (int j = 0; j < 4; j++)
          acc[i][j] = __builtin_amdgcn_mfma_f32_16x16x32_bf16(av[i], bv[j], acc[i][j], 0, 0, 0);
    }
    __syncthreads();
  }
  // ---- epilogue: out[t] = gate[t]*(acc+bias); stash tile if FG ----
  bf16_t* hs = smem;
  float bb[4];
#pragma unroll
  for (int j = 0; j < 4; j++) bb[j] = bias[n0 + wc + j * 16 + l15];
#pragma unroll
  for (int i = 0; i < 4; i++)
#pragma unroll
    for (int r = 0; r < 4; r++) {
      int rowL = wr + i * 16 + quad * 4 + r;
      int c = c0 + rowL;
      bool ok = c < count;
      int t = 0;
      float g = 0.f;
      if (ok) { t = tk[c]; g = gate[t]; }
#pragma unroll
      for (int j = 0; j < 4; j++) {
        int colL = wc + j * 16 + l15;
        float v = ok ? (acc[i][j][r] + bb[j]) * g : 0.f;
        bf16_t vb = (bf16_t)v;
        if (FG) hs[hsw(rowL, colL)] = vb;
        if (ok) outp[(size_t)t * DIM + n0 + colL] = vb;
      }
    }
  if (FG) {
    __syncthreads();
    fx4 lac0 = (fx4)0.0f, lac1 = (fx4)0.0f;
#pragma unroll
    for (int ks = 0; ks < 4; ks++) {
      bf16x8 bv = *(const bf16x8*)&WgPn[(((n0 >> 3) + ks * 4 + quad) * 8 + (l15 & 7)) * 8];
      bf16x8 av0 = *(const bf16x8*)&hs[hsw(wave * 32 + l15, ks * 32 + quad * 8)];
      bf16x8 av1 = *(const bf16x8*)&hs[hsw(wave * 32 + 16 + l15, ks * 32 + quad * 8)];
      lac0 = __builtin_amdgcn_mfma_f32_16x16x32_bf16(av0, bv, lac0, 0, 0, 0);
      lac1 = __builtin_amdgcn_mfma_f32_16x16x32_bf16(av1, bv, lac1, 0, 0, 0);
    }
    if (l15 < 8) {
#pragma unroll
      for (int r = 0; r < 4; r++) {
        int ca = c0 + wave * 32 + quad * 4 + r;
        int cb = ca + 16;
        if (ca < count) atomicAdd(&logits[tk[ca] * 8 + l15], lac0[r]);
        if (cb < count) atomicAdd(&logits[tk[cb] * 8 + l15], lac1[r]);
      }
    }
  }
}

// ---------------- sent += mean_s(o2) (h-part fused into dense) -------------
__global__ __launch_bounds__(256) void k_reduce_o2(
    const bf16_t* __restrict__ o2, float* __restrict__ sent) {
  const int tid = threadIdx.x;
  const int d8 = (tid & 127) * 8;
  const int sg = tid >> 7;
  const int b = blockIdx.y;
  const int s0 = blockIdx.x * 64 + sg * 32;
  float acc[8] = {0.f, 0.f, 0.f, 0.f, 0.f, 0.f, 0.f, 0.f};
  const size_t base = ((size_t)b * SEQ + s0) * DIM + d8;
  for (int i = 0; i < 32; i++) {
    union { bf16_t v[8]; uint4 u; } oo;
    oo.u = *(const uint4*)&o2[base + (size_t)i * DIM];
#pragma unroll
    for (int j = 0; j < 8; j++) acc[j] += (float)oo.v[j];
  }
#pragma unroll
  for (int j = 0; j < 8; j++)
    atomicAdd(&sent[b * DIM + d8 + j], acc[j] * (1.0f / SEQ));
}

// ---------------- loss: one block per batch, atomicAdd into out ------------
__global__ __launch_bounds__(256) void k_loss(
    const float* __restrict__ sent, const int* __restrict__ y,
    float* __restrict__ out) {
  const int b = blockIdx.x, tid = threadIdx.x;
  const float* sb = sent + b * DIM;
  __shared__ float red[256];
  float m = -1e30f;
  for (int d = tid; d < DIM; d += 256) m = fmaxf(m, sb[d]);
  red[tid] = m;
  __syncthreads();
  for (int s = 128; s; s >>= 1) {
    if (tid < s) red[tid] = fmaxf(red[tid], red[tid + s]);
    __syncthreads();
  }
  m = red[0];
  __syncthreads();
  float sum = 0.f;
  for (int d = tid; d < DIM; d += 256) sum += expf(sb[d] - m);
  red[tid] = sum;
  __syncthreads();
  for (int s = 128; s; s >>= 1) {
    if (tid < s) red[tid] += red[tid + s];
    __syncthreads();
  }
  if (tid == 0) atomicAdd(out, (m + logf(red[0]) - sb[y[b]]) * (1.0f / BATCH));
}

// ---------------------------------------------------------------------------
extern "C" void kernel_launch(void* const* d_in, const int* in_sizes, int n_in,
                              void* d_out, int out_size, void* d_ws, size_t ws_size,
                              hipStream_t stream) {
  (void)in_sizes; (void)n_in; (void)out_size; (void)ws_size;
  const float* x   = (const float*)d_in[0];
  const int*   y   = (const int*)d_in[1];
  const float* W1  = (const float*)d_in[2];
  const float* b1  = (const float*)d_in[3];
  const float* Wg2 = (const float*)d_in[4];
  const float* We2 = (const float*)d_in[5];
  const float* be2 = (const float*)d_in[6];
  const float* Wg3 = (const float*)d_in[7];
  const float* We3 = (const float*)d_in[8];
  const float* be3 = (const float*)d_in[9];

  char* p = (char*)d_ws;
  size_t off = 0;
  auto carve = [&](size_t bytes) -> char* {
    char* r = p + off;
    off += (bytes + 255) & ~(size_t)255;
    return r;
  };
  bf16_t* Wt   = (bf16_t*)carve((size_t)17 * DIM * DIM * 2);  // 0:W1t 1..8:We2t 9..16:We3t
  bf16_t* WgP  = (bf16_t*)carve(2 * 128 * 8 * 8 * 2);         // gate B-frag packs
  bf16_t* h    = (bf16_t*)carve((size_t)TOKS * DIM * 2);
  bf16_t* o1   = (bf16_t*)carve((size_t)TOKS * DIM * 2);
  bf16_t* o2   = (bf16_t*)carve((size_t)TOKS * DIM * 2);  // aliases xb lifetime
  float*  gate = (float*)carve(TOKS * 4);
  int*    tok  = (int*)carve(NEXP * CAP * 4);
  int*    cnt  = (int*)carve(NEXP * 4);
  // --- contiguous zero region: sent, zp, logits2, logits3 (single memset) --
  size_t zoff0 = off;
  float*  sent = (float*)carve(BATCH * DIM * 4);
  bf16_t* zp   = (bf16_t*)carve(4096);
  float*  lg2  = (float*)carve(TOKS * 8 * 4);
  float*  lg3  = (float*)carve(TOKS * 8 * 4);
  size_t zbytes = off - zoff0;
  bf16_t* xb   = o2;  // x-bf16 dead before o2 is born

  hipMemsetAsync(sent, 0, zbytes, stream);  // sent + zp + logits2 + logits3
  hipMemsetAsync(d_out, 0, 4, stream);      // loss accumulates via atomics

  // prep: W transpose+cvt (17x256 blocks) | Wg pack (2) | x cvt (8192)
  k_prep<<<PW_BLOCKS + 2 + CVT_BLOCKS, 256, 0, stream>>>(
      W1, We2, We3, Wg2, Wg3, x, Wt, WgP, xb);

  // dense pre-layer (+ logits2, + sent h-part)
  k_gemm_dense<<<(TOKS / 128) * (DIM / 128), 256, 0, stream>>>(
      xb, Wt, b1, WgP, h, lg2, sent);

  // MoE layer 2 (expert GEMM fuses logits3)
  k_route<<<NEXP, 1024, 0, stream>>>(lg2, tok, cnt, gate, o1);
  k_gemm_expert<true><<<NEXP * (CAP / 128) * (DIM / 128), 256, 0, stream>>>(
      h, Wt + (size_t)1 * DIM * DIM, be2, tok, cnt, gate, zp, o1,
      WgP + 128 * 8 * 8, lg3);

  // MoE layer 3
  k_route<<<NEXP, 1024, 0, stream>>>(lg3, tok, cnt, gate, o2);
  k_gemm_expert<false><<<NEXP * (CAP / 128) * (DIM / 128), 256, 0, stream>>>(
      o1, Wt + (size_t)9 * DIM * DIM, be3, tok, cnt, gate, zp, o2,
      nullptr, nullptr);

  // sent += mean_s(o2); CE loss
  k_reduce_o2<<<dim3(SEQ / 64, BATCH), 256, 0, stream>>>(o2, sent);
  k_loss<<<BATCH, 256, 0, stream>>>(sent, y, (float*)d_out);
}